// Round 15
// baseline (511.655 us; speedup 1.0000x reference)
//
#include <hip/hip_runtime.h>

#define T_SEQ   4096
#define DM      1024
#define NB      4
#define ROWS    (NB * T_SEQ)   /* 16384 */
#define NCH     64             /* chunks over time */
#define LCH     (T_SEQ / NCH)  /* 64 steps per chunk */

typedef unsigned short ushort_t;

typedef __attribute__((ext_vector_type(8))) short bf16x8;
typedef __attribute__((ext_vector_type(4))) float f32x4;

__device__ __forceinline__ float bf2f(ushort_t u) {
  return __uint_as_float(((unsigned int)u) << 16);
}
__device__ __forceinline__ ushort_t f2bf(float f) {
  unsigned int u = __float_as_uint(f);
  u += 0x7FFFu + ((u >> 16) & 1u);
  return (ushort_t)(u >> 16);
}
__device__ __forceinline__ unsigned cvtpk(float lo, float hi) {
  unsigned r;
  asm("v_cvt_pk_bf16_f32 %0, %1, %2" : "=v"(r) : "v"(lo), "v"(hi));
  return r;
}

__device__ __forceinline__ void async16(const void* g, void* l) {
  __builtin_amdgcn_global_load_lds(
      (const __attribute__((address_space(1))) unsigned int*)g,
      (__attribute__((address_space(3))) unsigned int*)l, 16, 0, 0);
}

// st_16x32 swizzled byte offset of (row,col) in a [rows]x64 bf16 tile.
// Proven zero-conflict read pattern (R3/R8/R12 measured SQ_LDS_BANK_CONFLICT=0).
__device__ __forceinline__ int fragoff(int row, int col) {
  int p = (((row >> 4) * 2 + (col >> 5)) << 10) + ((row & 15) << 6) + ((col & 31) << 1);
  return p ^ (((row >> 3) & 1) << 5);
}
// swizzled byte offset of (row,col) in a [rows]x32 bf16 tile (16x32 subtiles).
__device__ __forceinline__ int fragoffB32(int row, int col) {
  int p = ((row >> 4) << 10) + ((row & 15) << 6) + (col << 1);
  return p ^ (((row >> 3) & 1) << 5);
}

// ---------------- W cvt + bias pack (one launch) ----------------------------
__global__ __launch_bounds__(256)
void cvt_pack(const float* __restrict__ Wr, const float* __restrict__ Wk,
              const float* __restrict__ Wv, const float* __restrict__ Wo,
              const float* __restrict__ br, const float* __restrict__ bk,
              const float* __restrict__ bv, const float* __restrict__ bo,
              ushort_t* __restrict__ wb, float* __restrict__ biasP) {
  const int bid = blockIdx.x;
  if (bid < 2048) {
    const int n4 = (DM * DM);
    for (int i = bid * 256 + threadIdx.x; i < n4; i += 2048 * 256) {
      const int seg = i >> 18;
      const float* src = seg == 0 ? Wr : seg == 1 ? Wk : seg == 2 ? Wv : Wo;
      const float4 f = ((const float4*)src)[i & 262143];
      ushort4 o;
      o.x = f2bf(f.x); o.y = f2bf(f.y); o.z = f2bf(f.z); o.w = f2bf(f.w);
      ((ushort4*)wb)[i] = o;
    }
  } else {
    const int s = bid - 2048;
    const float* b = s == 0 ? br : s == 1 ? bk : s == 2 ? bv : bo;
    for (int i = threadIdx.x; i < DM; i += 256) biasP[s * DM + i] = b[i];
  }
}

// ---------------- final GEMM: unified 3-stage (R12/R14-proven) ---------------
template <typename OutT>
__global__ __launch_bounds__(512, 2)
void gemm3f(const ushort_t* __restrict__ A, const ushort_t* __restrict__ W,
            const float* __restrict__ bias, OutT* __restrict__ C,
            const int M, const int N, const int K) {
  constexpr int ABYTES = 16384;
  constexpr int BBYTES = 16384;
  __shared__ char smem[3 * (ABYTES + BBYTES)];
  const int T = K >> 5;
  const int nwg = (M >> 8) * (N >> 8);
  const int wg  = ((int)blockIdx.x & 7) * (nwg >> 3) + ((int)blockIdx.x >> 3);
  const int ntn = N >> 8;
  const int tm = wg / ntn, tn = wg % ntn;
  const int m0 = tm << 8, n0 = tn << 8;
  const int tid  = threadIdx.x;
  const int lane = tid & 63;
  const int wave = tid >> 6;
  const int wm128 = (wave >> 2) * 128;
  const int wn64  = (wave & 3) * 64;
  const int r15 = lane & 15;
  const int kq8 = (lane >> 4) * 8;

  int arow[2], acol[2];
  #pragma unroll
  for (int rho = 0; rho < 2; ++rho) {
    const int p = rho * 8192 + tid * 16;
    const int e = (p ^ (((p >> 9) & 1) << 5)) >> 1;
    arow[rho] = ((e >> 9) << 4) | ((e >> 5) & 15);
    acol[rho] = e & 31;
  }

  auto stageA = [&](int tile) {
    const int boff = (tile % 3) * ABYTES;
    #pragma unroll
    for (int rho = 0; rho < 2; ++rho) {
      const ushort_t* g2 = A + (size_t)(m0 + arow[rho]) * K + (tile << 5) + acol[rho];
      async16(g2, &smem[boff + rho * 8192 + tid * 16]);
    }
  };
  auto stageB = [&](int tile) {
    const int boff = 3 * ABYTES + (tile % 3) * BBYTES;
    #pragma unroll
    for (int rho = 0; rho < 2; ++rho) {
      const ushort_t* g2 = W + (size_t)(n0 + arow[rho]) * K + (tile << 5) + acol[rho];
      async16(g2, &smem[boff + rho * 8192 + tid * 16]);
    }
  };

  f32x4 acc[8][4];
  #pragma unroll
  for (int i = 0; i < 8; ++i)
    #pragma unroll
    for (int j = 0; j < 4; ++j)
      acc[i][j] = (f32x4){0.f, 0.f, 0.f, 0.f};
  bf16x8 bfr[4];

  stageA(0); stageB(0); stageA(1); stageB(1);
  asm volatile("s_waitcnt vmcnt(4)" ::: "memory");
  __builtin_amdgcn_s_barrier();

#define PH3(H, STG, TAILW)                                                       \
  {                                                                              \
    bf16x8 af[4];                                                                \
    _Pragma("unroll") for (int q = 0; q < 4; ++q)                                \
      af[q] = *(const bf16x8*)&smem[curA +                                       \
          fragoffB32(wm128 + (H) * 64 + q * 16 + r15, kq8)];                     \
    if ((H) == 0) {                                                              \
      _Pragma("unroll") for (int fj = 0; fj < 4; ++fj)                           \
        bfr[fj] = *(const bf16x8*)&smem[curB +                                   \
            fragoffB32(wn64 + (fj << 4) + r15, kq8)];                            \
    }                                                                            \
    STG();                                                                       \
    __builtin_amdgcn_s_barrier();                                                \
    __builtin_amdgcn_s_setprio(1);                                               \
    _Pragma("unroll") for (int q = 0; q < 4; ++q)                                \
      _Pragma("unroll") for (int fj = 0; fj < 4; ++fj)                           \
        acc[(H) * 4 + q][fj] = __builtin_amdgcn_mfma_f32_16x16x32_bf16(          \
            af[q], bfr[fj], acc[(H) * 4 + q][fj], 0, 0, 0);                      \
    __builtin_amdgcn_s_setprio(0);                                               \
    TAILW();                                                                     \
    __builtin_amdgcn_s_barrier();                                                \
  }

  for (int j = 0; j < T; ++j) {
    const int curA = (j % 3) * ABYTES;
    const int curB = 3 * ABYTES + (j % 3) * BBYTES;
    const bool p1 = (j + 1 < T), p2 = (j + 2 < T);
    auto sA = [&] { if (p2) stageA(j + 2); };
    auto sB = [&] { if (p2) stageB(j + 2); };
    auto nw = [&] {};
    auto tw = [&] {
      if (!p1) return;
      if (p2) asm volatile("s_waitcnt vmcnt(4)" ::: "memory");
      else    asm volatile("s_waitcnt vmcnt(0)" ::: "memory");
    };
    PH3(0, sA, nw);
    PH3(1, sB, tw);
  }
#undef PH3

  float bias4[4];
  #pragma unroll
  for (int fj = 0; fj < 4; ++fj) bias4[fj] = bias[n0 + wn64 + fj * 16 + r15];
  #pragma unroll
  for (int fi = 0; fi < 8; ++fi) {
    const int row0 = m0 + wm128 + fi * 16 + (lane >> 4) * 4;
    #pragma unroll
    for (int fj = 0; fj < 4; ++fj) {
      const int col = n0 + wn64 + fj * 16 + r15;
      #pragma unroll
      for (int r = 0; r < 4; ++r) {
        const float v = acc[fi][fj][r] + bias4[fj];
        if constexpr (sizeof(OutT) == 2) C[(size_t)(row0 + r) * N + col] = f2bf(v);
        else                             C[(size_t)(row0 + r) * N + col] = v;
      }
    }
  }
}

// ---------------- grouped proj GEMM: f32 A, reg-staged cvt -> bf16 LDS -------
// R11's kernel (passed correctness) with the launch_bounds fixed: LDS 128KB
// already caps at 1 wg/CU, so no min-waves spec -> 256 VGPR/wave budget, no
// spill. R3's 4-phase/BK=64/dbuf core; A: 8 global_load_dwordx4 for tile j+2
// at phase 0, cvt_pk + ds_write_b128 during iter j+1, consumed iter j+2.
__global__ __launch_bounds__(512)
void gemm3r(const float* __restrict__ Aq, const float* __restrict__ Ak,
            const float* __restrict__ Av, const ushort_t* __restrict__ Wb,
            const float* __restrict__ biasP, ushort_t* __restrict__ Cb,
            const int M, const int N, const int K) {
  __shared__ char smem[131072];   // A bf16: 2x32KB @0, B: 2x32KB @65536
  const int T = K >> 6;           // 16
  const int ntpg = (M >> 8) * (N >> 8);   // 256
  const int nwg  = 3 * ntpg;              // 768, %8==0
  const int wg = ((int)blockIdx.x & 7) * (nwg >> 3) + ((int)blockIdx.x >> 3);
  const int g     = wg / ntpg;
  const int local = wg % ntpg;
  const int ntn = N >> 8;
  const int tm = local / ntn, tn = local % ntn;
  const int m0 = tm << 8, n0 = tn << 8;
  const float*    Af   = g == 0 ? Aq : (g == 1 ? Ak : Av);
  const ushort_t* W    = Wb + (size_t)g * N * K;
  const float*    bias = biasP + g * N;
  ushort_t*       C    = Cb + (size_t)g * M * N;

  const int tid  = threadIdx.x;
  const int lane = tid & 63;
  const int wave = tid >> 6;
  const int wm128 = (wave >> 2) * 128;
  const int wn64  = (wave & 3) * 64;
  const int r15 = lane & 15;
  const int kq8 = (lane >> 4) * 8;

  int srow[2], scol[2];
  #pragma unroll
  for (int rho = 0; rho < 2; ++rho) {
    int p  = rho * 8192 + tid * 16;
    int pp = p ^ (((p >> 9) & 1) << 5);
    int e  = pp >> 1;
    int S = e >> 9, inr = e & 511;
    srow[rho] = ((S >> 1) << 4) + (inr >> 5);
    scol[rho] = ((S & 1) << 5) + (inr & 31);
  }
  int aRow[4], aCol[4];
  #pragma unroll
  for (int s = 0; s < 4; ++s) {
    aRow[s] = (s >> 1) * 128 + srow[s & 1];
    aCol[s] = scol[s & 1];
  }

  auto stageB = [&](int tile, int half) {
    const int boff = 65536 + ((tile & 1) << 15) + (half << 14);
    #pragma unroll
    for (int rho = 0; rho < 2; ++rho) {
      const ushort_t* gq = W + (size_t)(n0 + half * 128 + srow[rho]) * K + (tile << 6) + scol[rho];
      async16(gq, &smem[boff + rho * 8192 + tid * 16]);
    }
  };

  float4 regE[8], regO[8];

#define ALOAD(DST, TILE)                                                         \
  _Pragma("unroll") for (int s = 0; s < 4; ++s) {                                \
    const float* src_ = Af + (size_t)(m0 + aRow[s]) * K + ((TILE) << 6) + aCol[s]; \
    DST[2 * s]     = *(const float4*)src_;                                       \
    DST[2 * s + 1] = *(const float4*)(src_ + 4);                                 \
  }
#define AWRITE2(SRC, TILE, S0)                                                   \
  _Pragma("unroll") for (int s = (S0); s < (S0) + 2; ++s) {                      \
    uint4 w_;                                                                    \
    w_.x = cvtpk(SRC[2 * s][0], SRC[2 * s][1]);                                  \
    w_.y = cvtpk(SRC[2 * s][2], SRC[2 * s][3]);                                  \
    w_.z = cvtpk(SRC[2 * s + 1][0], SRC[2 * s + 1][1]);                          \
    w_.w = cvtpk(SRC[2 * s + 1][2], SRC[2 * s + 1][3]);                          \
    *(uint4*)&smem[(((TILE) & 1) << 15) + (s >> 1) * 16384 + (s & 1) * 8192 +    \
                   tid * 16] = w_;                                               \
  }

  f32x4 acc[8][4];
  #pragma unroll
  for (int i = 0; i < 8; ++i)
    #pragma unroll
    for (int j = 0; j < 4; ++j)
      acc[i][j] = (f32x4){0.f, 0.f, 0.f, 0.f};
  bf16x8 bf[4][2];

  ALOAD(regE, 0);
  stageB(0, 0); stageB(0, 1);
  ALOAD(regO, 1);
  stageB(1, 0); stageB(1, 1);
  AWRITE2(regE, 0, 0); AWRITE2(regE, 0, 2);
  asm volatile("s_waitcnt vmcnt(12)" ::: "memory");
  asm volatile("s_waitcnt lgkmcnt(0)" ::: "memory");
  __builtin_amdgcn_s_barrier();

#define RPHASE(Q, STG, TAILW)                                                    \
  {                                                                              \
    bf16x8 af[2][2];                                                             \
    _Pragma("unroll") for (int fl = 0; fl < 2; ++fl)                             \
      _Pragma("unroll") for (int ks = 0; ks < 2; ++ks)                           \
        af[fl][ks] = *(const bf16x8*)&smem[abase +                               \
            fragoff(wm128 + ((2 * (Q) + fl) << 4) + r15, (ks << 5) + kq8)];      \
    if ((Q) == 0) {                                                              \
      _Pragma("unroll") for (int fj = 0; fj < 4; ++fj)                           \
        _Pragma("unroll") for (int ks = 0; ks < 2; ++ks)                         \
          bf[fj][ks] = *(const bf16x8*)&smem[bbase +                             \
              fragoff(wn64 + (fj << 4) + r15, (ks << 5) + kq8)];                 \
    }                                                                            \
    STG                                                                          \
    __builtin_amdgcn_s_barrier();                                                \
    __builtin_amdgcn_s_setprio(1);                                               \
    _Pragma("unroll") for (int fl = 0; fl < 2; ++fl)                             \
      _Pragma("unroll") for (int fj = 0; fj < 4; ++fj)                           \
        _Pragma("unroll") for (int ks = 0; ks < 2; ++ks)                         \
          acc[2 * (Q) + fl][fj] = __builtin_amdgcn_mfma_f32_16x16x32_bf16(       \
              af[fl][ks], bf[fj][ks], acc[2 * (Q) + fl][fj], 0, 0, 0);           \
    __builtin_amdgcn_s_setprio(0);                                               \
    TAILW                                                                        \
    __builtin_amdgcn_s_barrier();                                                \
  }

#define ITER(J, LD, CV)                                                          \
  {                                                                              \
    const int j_ = (J);                                                          \
    const int abase = (j_ & 1) << 15;                                            \
    const int bbase = 65536 + ((j_ & 1) << 15);                                  \
    const bool pA = (j_ + 2 < T);                                                \
    const bool pC = (j_ + 1 < T);                                                \
    RPHASE(0, { if (pA) ALOAD(LD, j_ + 2); }, ;)                                 \
    RPHASE(1, { if (pC) { AWRITE2(CV, j_ + 1, 0); } }, ;)                        \
    RPHASE(2, { if (pA) stageB(j_ + 2, 0); if (pC) { AWRITE2(CV, j_ + 1, 2); } }, ;) \
    RPHASE(3, { if (pA) stageB(j_ + 2, 1); },                                    \
           { if (pA) asm volatile("s_waitcnt vmcnt(12)" ::: "memory");           \
             else    asm volatile("s_waitcnt vmcnt(0)" ::: "memory");            \
             asm volatile("s_waitcnt lgkmcnt(0)" ::: "memory"); })               \
  }

  for (int jj = 0; jj < T; jj += 2) {
    ITER(jj,     regE, regO);
    ITER(jj + 1, regO, regE);
  }
#undef ITER
#undef RPHASE
#undef ALOAD
#undef AWRITE2

  float bias4[4];
  #pragma unroll
  for (int fj = 0; fj < 4; ++fj) bias4[fj] = bias[n0 + wn64 + fj * 16 + r15];
  #pragma unroll
  for (int fi = 0; fi < 8; ++fi) {
    const int row0 = m0 + wm128 + fi * 16 + (lane >> 4) * 4;
    #pragma unroll
    for (int fj = 0; fj < 4; ++fj) {
      const int col = n0 + wn64 + fj * 16 + r15;
      #pragma unroll
      for (int r = 0; r < 4; ++r)
        C[(size_t)(row0 + r) * N + col] = f2bf(acc[fi][fj][r] + bias4[fj]);
    }
  }
}

// ---------------- WKV chunked scan ------------------------------------------
__global__ __launch_bounds__(256)
void wkv_pass1(const ushort_t* __restrict__ kp, const ushort_t* __restrict__ vp,
               const float* __restrict__ decay,
               float* __restrict__ s_num, float* __restrict__ s_den) {
  const int tid = threadIdx.x;
  const int grp = blockIdx.x & 3;
  const int c   = (blockIdx.x >> 2) & (NCH - 1);
  const int b   = (int)blockIdx.x >> 8;
  const int ch  = grp * 256 + tid;
  const float df = __expf(-__expf(decay[ch]));
  size_t idx = (size_t)b * T_SEQ * DM + (size_t)(c * LCH) * DM + ch;
  float num = 0.f, den = 0.f;
  for (int u = 0; u < LCH; ++u, idx += DM) {
    float kf = bf2f(kp[idx]);
    kf = fminf(fmaxf(kf, -10.f), 10.f);
    const float ek = __expf(kf);
    const float vv = bf2f(vp[idx]);
    num = fmaf(num, df, ek * vv);
    den = fmaf(den, df, ek);
  }
  const size_t si = ((size_t)b * NCH + c) * DM + ch;
  s_num[si] = num;
  s_den[si] = den;
}

// pass3 (pass2 fused): inline exclusive-prefix carry, then chunk replay.
__global__ __launch_bounds__(256)
void wkv_pass3(const ushort_t* __restrict__ kp, const ushort_t* __restrict__ vp,
               ushort_t* rg, const float* __restrict__ decay,
               const float* __restrict__ bonus,
               const float* __restrict__ s_num, const float* __restrict__ s_den) {
  const int tid = threadIdx.x;
  const int grp = blockIdx.x & 3;
  const int c   = (blockIdx.x >> 2) & (NCH - 1);
  const int b   = (int)blockIdx.x >> 8;
  const int ch  = grp * 256 + tid;
  const float w   = __expf(decay[ch]);
  const float df  = __expf(-w);
  const float dfL = __expf(-w * (float)LCH);
  const float eb  = __expf(bonus[ch]);

  float num = 0.f, den = 0.f;
  {
    size_t sp = (size_t)b * NCH * DM + ch;
    #pragma unroll 4
    for (int c2 = 0; c2 < c; ++c2, sp += DM) {
      num = fmaf(num, dfL, s_num[sp]);
      den = fmaf(den, dfL, s_den[sp]);
    }
  }

  size_t idx = (size_t)b * T_SEQ * DM + (size_t)(c * LCH) * DM + ch;
  for (int u = 0; u < LCH; ++u, idx += DM) {
    float kf = bf2f(kp[idx]);
    kf = fminf(fmaxf(kf, -10.f), 10.f);
    const float ek = __expf(kf);
    const float bw = eb * ek;
    const float vv = bf2f(vp[idx]);
    const float rr = bf2f(rg[idx]);
    const float numer = fmaf(bw, vv, num);
    const float denom = den + bw + 1e-6f;
    const float wkv = numer * __builtin_amdgcn_rcpf(denom);
    const float sig = __builtin_amdgcn_rcpf(1.f + __expf(-rr));
    rg[idx] = f2bf(sig * wkv);
    num = fmaf(num, df, ek * vv);
    den = fmaf(den, df, ek);
  }
}

// ---------------- launch -----------------------------------------------------
extern "C" void kernel_launch(void* const* d_in, const int* in_sizes, int n_in,
                              void* d_out, int out_size, void* d_ws, size_t ws_size,
                              hipStream_t stream) {
  const float* q   = (const float*)d_in[0];
  const float* ky  = (const float*)d_in[1];
  const float* vl  = (const float*)d_in[2];
  const float* Wr  = (const float*)d_in[3];
  const float* br  = (const float*)d_in[4];
  const float* Wk  = (const float*)d_in[5];
  const float* bk  = (const float*)d_in[6];
  const float* Wv  = (const float*)d_in[7];
  const float* bv  = (const float*)d_in[8];
  const float* Wo  = (const float*)d_in[9];
  const float* bo  = (const float*)d_in[10];
  const float* decay = (const float*)d_in[11];
  const float* bonus = (const float*)d_in[12];
  float* out = (float*)d_out;

  const size_t NE = (size_t)ROWS * DM;
  const size_t WE = (size_t)DM * DM;

  // ws layout (~111 MB): [wb 8MB][biasP 16KB][rp/G 32MB][kp 32MB][vp 32MB][s_num][s_den]
  ushort_t* wb = (ushort_t*)d_ws;
  float* biasP = (float*)(wb + 4 * WE);
  ushort_t* rp = (ushort_t*)(biasP + 4 * DM);
  ushort_t* kp = rp + NE;
  ushort_t* vp = kp + NE;
  float* s_num = (float*)(vp + NE);
  float* s_den = s_num + (size_t)NB * NCH * DM;
  ushort_t* G  = rp;

  dim3 cB(256);
  dim3 gemmBlk(512);
  dim3 projGrid(3 * (ROWS / 256) * (DM / 256));
  dim3 gemmGrid((ROWS / 256) * (DM / 256));
  dim3 scanGrid(NB * NCH * (DM / 256)), scanBlk(256);

  cvt_pack<<<dim3(2052), cB, 0, stream>>>(Wr, Wk, Wv, Wo, br, bk, bv, bo, wb, biasP);
  // grouped r/k/v projections: R11 reg-staged kernel, VGPR cap removed
  gemm3r<<<projGrid, gemmBlk, 0, stream>>>(q, ky, vl, wb, biasP, rp, ROWS, DM, DM);
  // WKV chunk-parallel scan + gate -> G (in place over rp); pass2 fused in
  wkv_pass1<<<scanGrid, scanBlk, 0, stream>>>(kp, vp, decay, s_num, s_den);
  wkv_pass3<<<scanGrid, scanBlk, 0, stream>>>(kp, vp, rp, decay, bonus, s_num, s_den);
  // output projection (A = G bf16 via gload_lds, f32 out)
  gemm3f<float><<<gemmGrid, gemmBlk, 0, stream>>>(G, wb + 3 * WE, biasP + 3 * DM, out, ROWS, DM, DM);
}

// Round 16
// 250.610 us; speedup vs baseline: 2.0416x; 2.0416x over previous
//
#include <hip/hip_runtime.h>

#define T_SEQ   4096
#define DM      1024
#define NB      4
#define ROWS    (NB * T_SEQ)   /* 16384 */
#define NCH     64             /* chunks over time */
#define LCH     (T_SEQ / NCH)  /* 64 steps per chunk */

typedef unsigned short ushort_t;

typedef __attribute__((ext_vector_type(8))) short bf16x8;
typedef __attribute__((ext_vector_type(4))) float f32x4;

__device__ __forceinline__ float bf2f(ushort_t u) {
  return __uint_as_float(((unsigned int)u) << 16);
}
__device__ __forceinline__ ushort_t f2bf(float f) {
  unsigned int u = __float_as_uint(f);
  u += 0x7FFFu + ((u >> 16) & 1u);
  return (ushort_t)(u >> 16);
}
__device__ __forceinline__ unsigned cvtpk(float lo, float hi) {
  unsigned r;
  asm("v_cvt_pk_bf16_f32 %0, %1, %2" : "=v"(r) : "v"(lo), "v"(hi));
  return r;
}

__device__ __forceinline__ void async16(const void* g, void* l) {
  __builtin_amdgcn_global_load_lds(
      (const __attribute__((address_space(1))) unsigned int*)g,
      (__attribute__((address_space(3))) unsigned int*)l, 16, 0, 0);
}

// st_16x32 swizzled byte offset of (row,col) in a [rows]x64 bf16 tile.
// Proven zero-conflict read pattern (R3/R8/R12 measured SQ_LDS_BANK_CONFLICT=0).
__device__ __forceinline__ int fragoff(int row, int col) {
  int p = (((row >> 4) * 2 + (col >> 5)) << 10) + ((row & 15) << 6) + ((col & 31) << 1);
  return p ^ (((row >> 3) & 1) << 5);
}
// swizzled byte offset of (row,col) in a [rows]x32 bf16 tile (16x32 subtiles).
__device__ __forceinline__ int fragoffB32(int row, int col) {
  int p = ((row >> 4) << 10) + ((row & 15) << 6) + (col << 1);
  return p ^ (((row >> 3) & 1) << 5);
}

// ---------------- W cvt + bias pack (one launch) ----------------------------
__global__ __launch_bounds__(256)
void cvt_pack(const float* __restrict__ Wr, const float* __restrict__ Wk,
              const float* __restrict__ Wv, const float* __restrict__ Wo,
              const float* __restrict__ br, const float* __restrict__ bk,
              const float* __restrict__ bv, const float* __restrict__ bo,
              ushort_t* __restrict__ wb, float* __restrict__ biasP) {
  const int bid = blockIdx.x;
  if (bid < 2048) {
    const int n4 = (DM * DM);
    for (int i = bid * 256 + threadIdx.x; i < n4; i += 2048 * 256) {
      const int seg = i >> 18;
      const float* src = seg == 0 ? Wr : seg == 1 ? Wk : seg == 2 ? Wv : Wo;
      const float4 f = ((const float4*)src)[i & 262143];
      ushort4 o;
      o.x = f2bf(f.x); o.y = f2bf(f.y); o.z = f2bf(f.z); o.w = f2bf(f.w);
      ((ushort4*)wb)[i] = o;
    }
  } else {
    const int s = bid - 2048;
    const float* b = s == 0 ? br : s == 1 ? bk : s == 2 ? bv : bo;
    for (int i = threadIdx.x; i < DM; i += 256) biasP[s * DM + i] = b[i];
  }
}

// ---------------- unified 3-stage GEMM (R12-proven, best measured) ----------
// BM=BN=256, BK=32, 8 waves, triple-buffered LDS, stage j+2 during iter j,
// one counted vmcnt per K-tile. A = f32 (fragoff column-permuted layout,
// 0 conflicts) or bf16 (fragoffB32). All A-paths zero-VGPR global_load_lds.
template <typename AT, typename OutT, int GROUPS>
__global__ __launch_bounds__(512, 2)
void gemm3(const AT* __restrict__ A0, const AT* __restrict__ A1,
           const AT* __restrict__ A2, const ushort_t* __restrict__ Wb,
           const float* __restrict__ biasP, OutT* __restrict__ Cb,
           const int M, const int N, const int K) {
  constexpr bool A_F32 = sizeof(AT) == 4;
  constexpr int ABYTES = A_F32 ? 32768 : 16384;
  constexpr int BBYTES = 16384;
  constexpr int AL = A_F32 ? 4 : 2;
  __shared__ char smem[3 * (ABYTES + BBYTES)];

  const int T = K >> 5;
  const int ntpg = (M >> 8) * (N >> 8);
  const int nwg  = GROUPS * ntpg;
  const int wg   = ((int)blockIdx.x & 7) * (nwg >> 3) + ((int)blockIdx.x >> 3);
  const int g     = wg / ntpg;
  const int local = wg % ntpg;
  const int ntn = N >> 8;
  const int tm = local / ntn, tn = local % ntn;
  const int m0 = tm << 8, n0 = tn << 8;
  const AT*       Ag   = g == 0 ? A0 : (g == 1 ? A1 : A2);
  const ushort_t* W    = Wb + (size_t)g * N * K;
  const float*    bias = biasP + g * N;
  OutT*           C    = Cb + (size_t)g * M * N;

  const int tid  = threadIdx.x;
  const int lane = tid & 63;
  const int wave = tid >> 6;
  const int wm128 = (wave >> 2) * 128;
  const int wn64  = (wave & 3) * 64;
  const int r15 = lane & 15;
  const int kq8 = (lane >> 4) * 8;

  int arow[AL], acol[AL];
  #pragma unroll
  for (int rho = 0; rho < AL; ++rho) {
    if constexpr (A_F32) {
      const int ph = (rho & 1) * 8192 + tid * 16;
      const int e = (ph ^ (((ph >> 9) & 1) << 5)) >> 1;
      const int S = e >> 9, inr = e & 511;
      arow[rho] = (rho >> 1) * 128 + (((S >> 1) << 4) + (inr >> 5));
      const int E = ((S & 1) << 5) + (inr & 31);
      acol[rho] = (((E & 31) >> 3) << 3) + ((E >> 5) << 2);
    } else {
      const int p = rho * 8192 + tid * 16;
      const int e = (p ^ (((p >> 9) & 1) << 5)) >> 1;
      arow[rho] = ((e >> 9) << 4) | ((e >> 5) & 15);
      acol[rho] = e & 31;
    }
  }
  int brow[2], bcol[2];
  #pragma unroll
  for (int rho = 0; rho < 2; ++rho) {
    const int p = rho * 8192 + tid * 16;
    const int e = (p ^ (((p >> 9) & 1) << 5)) >> 1;
    brow[rho] = ((e >> 9) << 4) | ((e >> 5) & 15);
    bcol[rho] = e & 31;
  }

  auto stageA = [&](int tile) {
    const int boff = (tile % 3) * ABYTES;
    #pragma unroll
    for (int rho = 0; rho < AL; ++rho) {
      const AT* g2 = Ag + (size_t)(m0 + arow[rho]) * K + (tile << 5) + acol[rho];
      if constexpr (A_F32)
        async16(g2, &smem[boff + (rho >> 1) * 16384 + (rho & 1) * 8192 + tid * 16]);
      else
        async16(g2, &smem[boff + rho * 8192 + tid * 16]);
    }
  };
  auto stageB = [&](int tile) {
    const int boff = 3 * ABYTES + (tile % 3) * BBYTES;
    #pragma unroll
    for (int rho = 0; rho < 2; ++rho) {
      const ushort_t* g2 = W + (size_t)(n0 + brow[rho]) * K + (tile << 5) + bcol[rho];
      async16(g2, &smem[boff + rho * 8192 + tid * 16]);
    }
  };

  auto rdAfrag = [&](int abase, int row) -> bf16x8 {
    if constexpr (A_F32) {
      const f32x4 lo = *(const f32x4*)&smem[abase + fragoff(row, kq8)];
      const f32x4 hi = *(const f32x4*)&smem[abase + fragoff(row, kq8 + 32)];
      union { uint4 u4; bf16x8 b; } cv;
      cv.u4.x = cvtpk(lo[0], lo[1]); cv.u4.y = cvtpk(lo[2], lo[3]);
      cv.u4.z = cvtpk(hi[0], hi[1]); cv.u4.w = cvtpk(hi[2], hi[3]);
      return cv.b;
    } else {
      return *(const bf16x8*)&smem[abase + fragoffB32(row, kq8)];
    }
  };

  f32x4 acc[8][4];
  #pragma unroll
  for (int i = 0; i < 8; ++i)
    #pragma unroll
    for (int j = 0; j < 4; ++j)
      acc[i][j] = (f32x4){0.f, 0.f, 0.f, 0.f};
  bf16x8 bfr[4];

  stageA(0); stageB(0); stageA(1); stageB(1);
  if constexpr (A_F32) asm volatile("s_waitcnt vmcnt(6)" ::: "memory");
  else                 asm volatile("s_waitcnt vmcnt(4)" ::: "memory");
  __builtin_amdgcn_s_barrier();

#define PH3(H, STG, TAILW)                                                       \
  {                                                                              \
    bf16x8 af[4];                                                                \
    _Pragma("unroll") for (int q = 0; q < 4; ++q)                                \
      af[q] = rdAfrag(curA, wm128 + (H) * 64 + q * 16 + r15);                    \
    if ((H) == 0) {                                                              \
      _Pragma("unroll") for (int fj = 0; fj < 4; ++fj)                           \
        bfr[fj] = *(const bf16x8*)&smem[curB +                                   \
            fragoffB32(wn64 + (fj << 4) + r15, kq8)];                            \
    }                                                                            \
    STG();                                                                       \
    __builtin_amdgcn_s_barrier();                                                \
    __builtin_amdgcn_s_setprio(1);                                               \
    _Pragma("unroll") for (int q = 0; q < 4; ++q)                                \
      _Pragma("unroll") for (int fj = 0; fj < 4; ++fj)                           \
        acc[(H) * 4 + q][fj] = __builtin_amdgcn_mfma_f32_16x16x32_bf16(          \
            af[q], bfr[fj], acc[(H) * 4 + q][fj], 0, 0, 0);                      \
    __builtin_amdgcn_s_setprio(0);                                               \
    TAILW();                                                                     \
    __builtin_amdgcn_s_barrier();                                                \
  }

  for (int j = 0; j < T; ++j) {
    const int curA = (j % 3) * ABYTES;
    const int curB = 3 * ABYTES + (j % 3) * BBYTES;
    const bool p1 = (j + 1 < T), p2 = (j + 2 < T);
    auto sA = [&] { if (p2) stageA(j + 2); };
    auto sB = [&] { if (p2) stageB(j + 2); };
    auto nw = [&] {};
    auto tw = [&] {
      if (!p1) return;
      if (p2) {
        if constexpr (A_F32) asm volatile("s_waitcnt vmcnt(6)" ::: "memory");
        else                 asm volatile("s_waitcnt vmcnt(4)" ::: "memory");
      } else {
        asm volatile("s_waitcnt vmcnt(0)" ::: "memory");
      }
    };
    PH3(0, sA, nw);
    PH3(1, sB, tw);
  }
#undef PH3

  float bias4[4];
  #pragma unroll
  for (int fj = 0; fj < 4; ++fj) bias4[fj] = bias[n0 + wn64 + fj * 16 + r15];
  #pragma unroll
  for (int fi = 0; fi < 8; ++fi) {
    const int row0 = m0 + wm128 + fi * 16 + (lane >> 4) * 4;
    #pragma unroll
    for (int fj = 0; fj < 4; ++fj) {
      const int col = n0 + wn64 + fj * 16 + r15;
      #pragma unroll
      for (int r = 0; r < 4; ++r) {
        const float v = acc[fi][fj][r] + bias4[fj];
        if constexpr (sizeof(OutT) == 2) C[(size_t)(row0 + r) * N + col] = f2bf(v);
        else                             C[(size_t)(row0 + r) * N + col] = v;
      }
    }
  }
}

// ---------------- WKV chunked scan ------------------------------------------
// pass1: per-chunk local sums (zero init).
__global__ __launch_bounds__(256)
void wkv_pass1(const ushort_t* __restrict__ kp, const ushort_t* __restrict__ vp,
               const float* __restrict__ decay,
               float* __restrict__ s_num, float* __restrict__ s_den) {
  const int tid = threadIdx.x;
  const int grp = blockIdx.x & 3;
  const int c   = (blockIdx.x >> 2) & (NCH - 1);
  const int b   = (int)blockIdx.x >> 8;
  const int ch  = grp * 256 + tid;
  const float df = __expf(-__expf(decay[ch]));
  size_t idx = (size_t)b * T_SEQ * DM + (size_t)(c * LCH) * DM + ch;
  float num = 0.f, den = 0.f;
  for (int u = 0; u < LCH; ++u, idx += DM) {
    float kf = bf2f(kp[idx]);
    kf = fminf(fmaxf(kf, -10.f), 10.f);
    const float ek = __expf(kf);
    const float vv = bf2f(vp[idx]);
    num = fmaf(num, df, ek * vv);
    den = fmaf(den, df, ek);
  }
  const size_t si = ((size_t)b * NCH + c) * DM + ch;
  s_num[si] = num;
  s_den[si] = den;
}

// pass3 (pass2 fused): each block computes its own exclusive-prefix carry
// inline (<= 63 coalesced loads + identical-order FMA chain), then replays
// its chunk. rg: r proj IN, gated output OUT (same buffer; per-index read
// precedes write; rp regenerated every launch).
__global__ __launch_bounds__(256)
void wkv_pass3(const ushort_t* __restrict__ kp, const ushort_t* __restrict__ vp,
               ushort_t* rg, const float* __restrict__ decay,
               const float* __restrict__ bonus,
               const float* __restrict__ s_num, const float* __restrict__ s_den) {
  const int tid = threadIdx.x;
  const int grp = blockIdx.x & 3;
  const int c   = (blockIdx.x >> 2) & (NCH - 1);
  const int b   = (int)blockIdx.x >> 8;
  const int ch  = grp * 256 + tid;
  const float w   = __expf(decay[ch]);
  const float df  = __expf(-w);
  const float dfL = __expf(-w * (float)LCH);
  const float eb  = __expf(bonus[ch]);

  // inline exclusive prefix over chunks 0..c-1 (decayed by dfL per chunk)
  float num = 0.f, den = 0.f;
  {
    size_t sp = (size_t)b * NCH * DM + ch;
    #pragma unroll 4
    for (int c2 = 0; c2 < c; ++c2, sp += DM) {
      num = fmaf(num, dfL, s_num[sp]);
      den = fmaf(den, dfL, s_den[sp]);
    }
  }

  size_t idx = (size_t)b * T_SEQ * DM + (size_t)(c * LCH) * DM + ch;
  for (int u = 0; u < LCH; ++u, idx += DM) {
    float kf = bf2f(kp[idx]);
    kf = fminf(fmaxf(kf, -10.f), 10.f);
    const float ek = __expf(kf);
    const float bw = eb * ek;
    const float vv = bf2f(vp[idx]);
    const float rr = bf2f(rg[idx]);
    const float numer = fmaf(bw, vv, num);
    const float denom = den + bw + 1e-6f;
    const float wkv = numer * __builtin_amdgcn_rcpf(denom);
    const float sig = __builtin_amdgcn_rcpf(1.f + __expf(-rr));
    rg[idx] = f2bf(sig * wkv);
    num = fmaf(num, df, ek * vv);
    den = fmaf(den, df, ek);
  }
}

// ---------------- launch -----------------------------------------------------
extern "C" void kernel_launch(void* const* d_in, const int* in_sizes, int n_in,
                              void* d_out, int out_size, void* d_ws, size_t ws_size,
                              hipStream_t stream) {
  const float* q   = (const float*)d_in[0];
  const float* ky  = (const float*)d_in[1];
  const float* vl  = (const float*)d_in[2];
  const float* Wr  = (const float*)d_in[3];
  const float* br  = (const float*)d_in[4];
  const float* Wk  = (const float*)d_in[5];
  const float* bk  = (const float*)d_in[6];
  const float* Wv  = (const float*)d_in[7];
  const float* bv  = (const float*)d_in[8];
  const float* Wo  = (const float*)d_in[9];
  const float* bo  = (const float*)d_in[10];
  const float* decay = (const float*)d_in[11];
  const float* bonus = (const float*)d_in[12];
  float* out = (float*)d_out;

  const size_t NE = (size_t)ROWS * DM;
  const size_t WE = (size_t)DM * DM;

  // ws layout (~111 MB): [wb 8MB][biasP 16KB][rp/G 32MB][kp 32MB][vp 32MB][s_num][s_den]
  ushort_t* wb = (ushort_t*)d_ws;
  float* biasP = (float*)(wb + 4 * WE);
  ushort_t* rp = (ushort_t*)(biasP + 4 * DM);
  ushort_t* kp = rp + NE;
  ushort_t* vp = kp + NE;
  float* s_num = (float*)(vp + NE);
  float* s_den = s_num + (size_t)NB * NCH * DM;
  ushort_t* G  = rp;

  dim3 cB(256);
  dim3 gemmBlk(512);
  dim3 projGrid(3 * (ROWS / 256) * (DM / 256));
  dim3 gemmGrid((ROWS / 256) * (DM / 256));
  dim3 scanGrid(NB * NCH * (DM / 256)), scanBlk(256);

  cvt_pack<<<dim3(2052), cB, 0, stream>>>(Wr, Wk, Wv, Wo, br, bk, bv, bo, wb, biasP);
  // grouped r/k/v projections, f32 A direct, 3-stage pipeline, 0-conflict layout
  gemm3<float, ushort_t, 3><<<projGrid, gemmBlk, 0, stream>>>(
      q, ky, vl, wb, biasP, rp, ROWS, DM, DM);
  // WKV chunk-parallel scan + gate -> G (in place over rp); pass2 fused in
  wkv_pass1<<<scanGrid, scanBlk, 0, stream>>>(kp, vp, decay, s_num, s_den);
  wkv_pass3<<<scanGrid, scanBlk, 0, stream>>>(kp, vp, rp, decay, bonus, s_num, s_den);
  // output projection (A = G bf16 via gload_lds, f32 out), 3-stage pipeline
  gemm3<ushort_t, float, 1><<<gemmGrid, gemmBlk, 0, stream>>>(
      G, G, G, wb + 3 * WE, biasP + 3 * DM, out, ROWS, DM, DM);
}